// Round 14
// baseline (628.129 us; speedup 1.0000x reference)
//
#include <hip/hip_runtime.h>

typedef __attribute__((ext_vector_type(4))) float f32x4;
typedef __attribute__((ext_vector_type(8))) short s16x8;

#define MFMA16(a, b, c) __builtin_amdgcn_mfma_f32_16x16x32_bf16((a), (b), (c), 0, 0, 0)

__device__ __forceinline__ float hsig(float x) {
    return fminf(fmaxf(0.2f * x + 0.5f, 0.0f), 1.0f);
}

__device__ __forceinline__ unsigned short bf16rne(float v) {
    unsigned u = __float_as_uint(v);
    u += 0x7FFFu + ((u >> 16) & 1u);
    return (unsigned short)(u >> 16);
}
__device__ __forceinline__ void split2(float v, unsigned short& h, unsigned short& l) {
    h = bf16rne(v);
    float hv = __uint_as_float((unsigned)h << 16);
    l = bf16rne(v - hv);
}

// ---- weight prep: reorder to MFMA A-fragment order, GATE-INTERLEAVED rows ----
// Bw layout: [ks][ hi: nfrag(16) x lane(64) x 8 | lo: same ]  (16384 ushorts per ks)
// Row n is the OUTPUT channel in interleaved order c' = 4*feature + gate, so a
// lane's 4 C/D q-registers hold the 4 gates of one feature (no z-exchange).
template<int KHW, int CX, int NS>
__global__ __launch_bounds__(256)
void prep_w(const float* __restrict__ Kw, const float* __restrict__ Rw,
            unsigned short* __restrict__ Bw)
{
    int gid = blockIdx.x * 256 + threadIdx.x;
    if (gid >= NS * 1024) return;
    int lane  = gid & 63;
    int nfrag = (gid >> 6) & 15;
    int ks    = gid >> 10;
    int n   = nfrag * 16 + (lane & 15);       // interleaved channel c'
    int src = (n & 3) * 64 + (n >> 2);        // original col: gate*64 + feature
    int kl  = (lane >> 4) * 8;
    constexpr int KX = KHW * CX;
    s16x8 vh, vl;
#pragma unroll
    for (int j = 0; j < 8; ++j) {
        int kg = ks * 32 + kl + j;
        float w = (kg < KX) ? Kw[(long)kg * 256 + src]
                            : Rw[(long)(kg - KX) * 256 + src];
        unsigned short h, l;
        split2(w, h, l);
        vh[j] = (short)h;
        vl[j] = (short)l;
    }
    unsigned short* o = Bw + (long)ks * 16384 + nfrag * 512 + lane * 8;
    *(s16x8*)o = vh;
    *(s16x8*)(o + 8192) = vl;
}

// ---- stage zero-padded tile as bf16 hi/lo planes, chunk-major [c/8][pixel][8] ----
template<int C, int TS, int PAD, int CST>
__device__ __forceinline__ void stage_split(const float* __restrict__ gp,
                                            unsigned short* __restrict__ hi_,
                                            unsigned short* __restrict__ lo_,
                                            int ty0, int tx0, int tid)
{
    constexpr int CH = C / 8;
    constexpr int NP = TS * TS;
    for (int i = tid; i < NP * CH; i += 512) {
        int ch = i % CH;
        int p  = i / CH;
        int py = p / TS, px = p % TS;
        int iy = ty0 + py - PAD, ix = tx0 + px - PAD;
        float v[8];
        if (iy >= 0 && iy < 64 && ix >= 0 && ix < 64) {
            const float* s = gp + ((long)(iy * 64 + ix)) * C + ch * 8;
            f32x4 a = *(const f32x4*)s;
            f32x4 b = *(const f32x4*)(s + 4);
#pragma unroll
            for (int j = 0; j < 4; ++j) { v[j] = a[j]; v[4 + j] = b[j]; }
        } else {
#pragma unroll
            for (int j = 0; j < 8; ++j) v[j] = 0.0f;
        }
        s16x8 vh, vl;
#pragma unroll
        for (int j = 0; j < 8; ++j) {
            unsigned short h, l;
            split2(v[j], h, l);
            vh[j] = (short)h;
            vl[j] = (short)l;
        }
        *(s16x8*)(hi_ + ch * CST + p * 8) = vh;
        *(s16x8*)(lo_ + ch * CST + p * 8) = vl;
    }
}

// ---- ConvLSTM step body: SWAPPED-OPERAND MFMA (z^T = W * X) ----
// 8 waves; wave w owns channels [32w, 32w+32) (2 A-frags) x ALL 64 pixels
// (4 B-frags), full K. Output D[row=channel][col=pixel]: pixel = lane&15,
// channel = (lane>>4)*4 + q. With gate-interleaved channels c' = 4f+g, each
// lane's q-regs = the 4 gates of one feature at one pixel -> the whole LSTM
// cell update is per-lane in registers: NO z-exchange, NO epilogue barriers.
template<int KW, int CX, int TS, int NS, int XS>
__device__ __forceinline__ void lstm_body(
    unsigned short* __restrict__ smem,
    const float* __restrict__ xin, long xbstride,
    const float* __restrict__ hin,
    const unsigned short* __restrict__ Bg,
    const float* __restrict__ bias,
    float* __restrict__ c_buf,        // feature-major: [b][f][4096]
    float* __restrict__ h_out,
    float* __restrict__ y_out, long ybstride,
    int b)
{
    constexpr int PAD = KW / 2;
    constexpr int NP  = TS * TS;
    constexpr int CHX = CX / 8;
    constexpr int CST = NP * 8;              // chunk stride (ushorts), r12 layout
    constexpr int XPLANE = CHX * CST;
    constexpr int HPLANE = 8 * CST;

    unsigned short* sxh = smem;
    unsigned short* sxl = sxh + XPLANE;
    unsigned short* shh = sxl + XPLANE;
    unsigned short* shl = shh + HPLANE;

    const int tid  = threadIdx.x;
    const int lane = tid & 63, wid = tid >> 6;
    const int ty0 = blockIdx.y * 8, tx0 = blockIdx.x * 8;

    // W fragment stream: wave w owns nfrags {2w, 2w+1} = channels [32w, 32w+32)
    const unsigned short* bq = Bg + (2 * wid) * 512 + lane * 8;

    stage_split<CX, TS, PAD, CST>(xin + (long)b * xbstride, sxh, sxl, ty0, tx0, tid);
    stage_split<64, TS, PAD, CST>(hin + (long)b * 4096 * 64, shh, shl, ty0, tx0, tid);
    __syncthreads();

    f32x4 acc[2][4];   // [cf][pf]
#pragma unroll
    for (int cf = 0; cf < 2; ++cf)
#pragma unroll
        for (int pf = 0; pf < 4; ++pf)
#pragma unroll
            for (int q = 0; q < 4; ++q) acc[cf][pf][q] = 0.0f;

    // thread-const X offsets (ushort units). pixel p = pf*16 + (lane&15)
    const int pb  = lane & 15;
    const int kq  = (lane >> 4) * CST;
    const int av0 = (((pb      >> 3) * TS) + (pb      & 7)) * 8 + kq;
    const int av1 = ((((pb+16) >> 3) * TS) + ((pb+16) & 7)) * 8 + kq;
    const int av2 = ((((pb+32) >> 3) * TS) + ((pb+32) & 7)) * 8 + kq;
    const int av3 = ((((pb+48) >> 3) * TS) + ((pb+48) & 7)) * 8 + kq;

    // one k-step: W from L2 (4x16B), X from LDS (8x16B, immediate offsets),
    // 24 MFMA in 3 passes (WhXh, WlXh, WhXl), 8 independent acc chains.
#define KSTEP(PH, PL, SO)                                                 \
    {                                                                     \
        s16x8 Wh0 = *(const s16x8*)(bq);                                  \
        s16x8 Wh1 = *(const s16x8*)(bq + 512);                            \
        s16x8 Wl0 = *(const s16x8*)(bq + 8192);                           \
        s16x8 Wl1 = *(const s16x8*)(bq + 8192 + 512);                     \
        s16x8 X0h = *(const s16x8*)((PH) + (SO) + av0);                   \
        s16x8 X1h = *(const s16x8*)((PH) + (SO) + av1);                   \
        s16x8 X2h = *(const s16x8*)((PH) + (SO) + av2);                   \
        s16x8 X3h = *(const s16x8*)((PH) + (SO) + av3);                   \
        s16x8 X0l = *(const s16x8*)((PL) + (SO) + av0);                   \
        s16x8 X1l = *(const s16x8*)((PL) + (SO) + av1);                   \
        s16x8 X2l = *(const s16x8*)((PL) + (SO) + av2);                   \
        s16x8 X3l = *(const s16x8*)((PL) + (SO) + av3);                   \
        __builtin_amdgcn_s_setprio(1);                                    \
        acc[0][0] = MFMA16(Wh0, X0h, acc[0][0]);                          \
        acc[1][0] = MFMA16(Wh1, X0h, acc[1][0]);                          \
        acc[0][1] = MFMA16(Wh0, X1h, acc[0][1]);                          \
        acc[1][1] = MFMA16(Wh1, X1h, acc[1][1]);                          \
        acc[0][2] = MFMA16(Wh0, X2h, acc[0][2]);                          \
        acc[1][2] = MFMA16(Wh1, X2h, acc[1][2]);                          \
        acc[0][3] = MFMA16(Wh0, X3h, acc[0][3]);                          \
        acc[1][3] = MFMA16(Wh1, X3h, acc[1][3]);                          \
        acc[0][0] = MFMA16(Wh0, X0l, acc[0][0]);                          \
        acc[1][0] = MFMA16(Wh1, X0l, acc[1][0]);                          \
        acc[0][1] = MFMA16(Wh0, X1l, acc[0][1]);                          \
        acc[1][1] = MFMA16(Wh1, X1l, acc[1][1]);                          \
        acc[0][2] = MFMA16(Wh0, X2l, acc[0][2]);                          \
        acc[1][2] = MFMA16(Wh1, X2l, acc[1][2]);                          \
        acc[0][3] = MFMA16(Wh0, X3l, acc[0][3]);                          \
        acc[1][3] = MFMA16(Wh1, X3l, acc[1][3]);                          \
        acc[0][0] = MFMA16(Wl0, X0h, acc[0][0]);                          \
        acc[1][0] = MFMA16(Wl1, X0h, acc[1][0]);                          \
        acc[0][1] = MFMA16(Wl0, X1h, acc[0][1]);                          \
        acc[1][1] = MFMA16(Wl1, X1h, acc[1][1]);                          \
        acc[0][2] = MFMA16(Wl0, X2h, acc[0][2]);                          \
        acc[1][2] = MFMA16(Wl1, X2h, acc[1][2]);                          \
        acc[0][3] = MFMA16(Wl0, X3h, acc[0][3]);                          \
        acc[1][3] = MFMA16(Wl1, X3h, acc[1][3]);                          \
        __builtin_amdgcn_s_setprio(0);                                    \
        bq += 16384;                                                      \
    }

    // ---- x-phase (k-step order matches prep_w: ks = tap [CX=32] or
    //      ks = 2*tap + c2 [CX=64], tap = kh*KW + kw) ----
    if (CX == 32) {
#pragma unroll 1
        for (int kh = 0; kh < KW; ++kh) {
#pragma unroll
            for (int kw = 0; kw < KW; ++kw) {
                KSTEP(sxh, sxl, (kh * TS + kw) * 8);
            }
        }
    } else {
#pragma unroll 1
        for (int kh = 0; kh < KW; ++kh) {
#pragma unroll
            for (int kw = 0; kw < KW; ++kw) {
#pragma unroll
                for (int c2 = 0; c2 < 2; ++c2) {
                    KSTEP(sxh, sxl, c2 * 4 * CST + (kh * TS + kw) * 8);
                }
            }
        }
    }
    // ---- h-phase (C=64): ks-XS = 2*tap + c2 ----
#pragma unroll 1
    for (int kh = 0; kh < KW; ++kh) {
#pragma unroll
        for (int kw = 0; kw < KW; ++kw) {
#pragma unroll
            for (int c2 = 0; c2 < 2; ++c2) {
                KSTEP(shh, shl, c2 * 4 * CST + (kh * TS + kw) * 8);
            }
        }
    }
#undef KSTEP

    // ---- per-lane gate epilogue: NO barriers, NO LDS ----
    // Lane holds, per (cf,pf): gates q={i,f,g,o} of feature
    // f = wid*8 + cf*4 + (lane>>4) at pixel p = pf*16 + (lane&15).
    const int pxb = lane & 15;
    const int fq  = lane >> 4;
#pragma unroll
    for (int cf = 0; cf < 2; ++cf) {
        const int f = wid * 8 + cf * 4 + fq;
        const float bi  = bias[f];
        const float bfr = bias[64 + f];
        const float bg  = bias[128 + f];
        const float bo  = bias[192 + f];
#pragma unroll
        for (int pf = 0; pf < 4; ++pf) {
            int p  = pf * 16 + pxb;
            int yy = ty0 + (p >> 3), xx = tx0 + (p & 7);
            int gp = yy * 64 + xx;                       // pixel in 64x64
            long o  = ((long)(b * 64) + yy) * 64 * 64 + (long)xx * 64 + f;
            long oc = ((long)(b * 64 + f)) * 4096 + gp;  // c: feature-major
            float zi = acc[cf][pf][0] + bi;
            float zf = acc[cf][pf][1] + bfr;
            float zg = acc[cf][pf][2] + bg;
            float zo = acc[cf][pf][3] + bo;
            float cv = c_buf[oc];
            float cn = hsig(zf) * cv + hsig(zi) * tanhf(zg);
            c_buf[oc] = cn;
            float hn = hsig(zo) * tanhf(cn);
            h_out[o] = hn;
            y_out[(long)b * ybstride + (long)gp * 64 + f] = fmaxf(hn, 0.0f);
        }
    }
}

// ---- fused dual-layer launch: z<4 -> layer1 step t, z>=4 -> layer2 step t-1 ----
// (512,2): no forced register cap; r12's 52 arch + 32 acc regs give natural
// 2-block/CU co-residency (occ ~34%).
__global__ __launch_bounds__(512, 2)
void lstm_fused(
    const float* __restrict__ x1, const float* __restrict__ h1in,
    const unsigned short* __restrict__ B1g, const float* __restrict__ bias1,
    float* __restrict__ c1, float* __restrict__ h1out, float* __restrict__ y1out,
    const float* __restrict__ x2, const float* __restrict__ h2in,
    const unsigned short* __restrict__ B2g, const float* __restrict__ bias2,
    float* __restrict__ c2, float* __restrict__ h2out, float* __restrict__ y2out,
    int mode)
{
    __shared__ __align__(16) unsigned short smem[27648];  // 55296 B (L1 stage)
    const int z = blockIdx.z;
    const int b = z & 3;
    const bool doL2 = (mode == 1) || (z >= 4);
    if (!doL2) {
        lstm_body<5, 32, 12, 75, 25>(smem, x1, (long)8 * 4096 * 32, h1in,
                                     B1g, bias1, c1, h1out,
                                     y1out, (long)8 * 4096 * 64, b);
    } else {
        lstm_body<3, 64, 10, 36, 18>(smem, x2, (long)8 * 4096 * 64, h2in,
                                     B2g, bias2, c2, h2out,
                                     y2out, (long)8 * 4096 * 64, b);
    }
}

extern "C" void kernel_launch(void* const* d_in, const int* in_sizes, int n_in,
                              void* d_out, int out_size, void* d_ws, size_t ws_size,
                              hipStream_t stream)
{
    const float* x  = (const float*)d_in[0];
    const float* K1 = (const float*)d_in[1];
    const float* R1 = (const float*)d_in[2];
    const float* b1 = (const float*)d_in[3];
    const float* K2 = (const float*)d_in[4];
    const float* R2 = (const float*)d_in[5];
    const float* b2 = (const float*)d_in[6];
    float* out = (float*)d_out;

    const long HW   = 4096;
    const long SZ_S = HW * 64 * 4;      // 1,048,576 floats per [B,H,W,64]
    const long SZ_Y = SZ_S * 8;

    float* ws  = (float*)d_ws;
    float* y1  = ws;                    // 8,388,608 f32 ([B][T][HW][64])
    float* h1a = y1 + SZ_Y;
    float* h1b = h1a + SZ_S;
    float* h2a = h1b + SZ_S;
    float* h2b = h2a + SZ_S;
    float* c1  = h2b + SZ_S;
    float* c2  = c1 + SZ_S;
    unsigned short* B1 = (unsigned short*)(c2 + SZ_S);   // 75*16384 ushorts
    unsigned short* B2 = B1 + (long)75 * 16384;          // 36*16384 ushorts

    // weight prep
    prep_w<25, 32, 75><<<300, 256, 0, stream>>>(K1, R1, B1);
    prep_w<9,  64, 36><<<144, 256, 0, stream>>>(K2, R2, B2);

    hipMemsetAsync(h1a, 0, (size_t)SZ_S * sizeof(float), stream);
    hipMemsetAsync(c1,  0, (size_t)SZ_S * sizeof(float), stream);
    hipMemsetAsync(h2a, 0, (size_t)SZ_S * sizeof(float), stream);
    hipMemsetAsync(c2,  0, (size_t)SZ_S * sizeof(float), stream);

    float* hp1 = h1a; float* hn1 = h1b;
    float* hp2 = h2a; float* hn2 = h2b;

    for (int t = 0; t <= 8; ++t) {
        const int mode = (t == 0) ? 0 : (t == 8) ? 1 : 2;
        const int t1  = (t <= 7) ? t : 7;       // L1 timestep (unused at t=8)
        const int tm1 = (t >= 1) ? t - 1 : 0;   // L2 timestep (unused at t=0)
        dim3 grid(8, 8, mode == 2 ? 8 : 4);
        lstm_fused<<<grid, 512, 0, stream>>>(
            x  + (long)t1 * HW * 32,  hp1, B1, b1, c1, hn1,
            y1 + (long)t1 * HW * 64,
            y1 + (long)tm1 * HW * 64, hp2, B2, b2, c2, hn2,
            out + (long)tm1 * HW * 64,
            mode);
        if (mode != 1) { float* tmp = hp1; hp1 = hn1; hn1 = tmp; }
        if (mode != 0) { float* tmp = hp2; hp2 = hn2; hn2 = tmp; }
    }
}

// Round 15
// 617.435 us; speedup vs baseline: 1.0173x; 1.0173x over previous
//
#include <hip/hip_runtime.h>

typedef __attribute__((ext_vector_type(4))) float f32x4;
typedef __attribute__((ext_vector_type(8))) short s16x8;

#define MFMA16(a, b, c) __builtin_amdgcn_mfma_f32_16x16x32_bf16((a), (b), (c), 0, 0, 0)

__device__ __forceinline__ float hsig(float x) {
    return fminf(fmaxf(0.2f * x + 0.5f, 0.0f), 1.0f);
}

__device__ __forceinline__ unsigned short bf16rne(float v) {
    unsigned u = __float_as_uint(v);
    u += 0x7FFFu + ((u >> 16) & 1u);
    return (unsigned short)(u >> 16);
}
__device__ __forceinline__ void split2(float v, unsigned short& h, unsigned short& l) {
    h = bf16rne(v);
    float hv = __uint_as_float((unsigned)h << 16);
    l = bf16rne(v - hv);
}

// ---- weight prep: reorder to MFMA A-fragment order, GATE-INTERLEAVED rows ----
// Bw layout: [ks][ hi: nfrag(16) x lane(64) x 8 | lo: same ]  (16384 ushorts per ks)
// Row n is the OUTPUT channel in interleaved order c' = 4*feature + gate, so a
// lane's 4 C/D q-registers hold the 4 gates of one feature (no z-exchange).
template<int KHW, int CX, int NS>
__global__ __launch_bounds__(256)
void prep_w(const float* __restrict__ Kw, const float* __restrict__ Rw,
            unsigned short* __restrict__ Bw)
{
    int gid = blockIdx.x * 256 + threadIdx.x;
    if (gid >= NS * 1024) return;
    int lane  = gid & 63;
    int nfrag = (gid >> 6) & 15;
    int ks    = gid >> 10;
    int n   = nfrag * 16 + (lane & 15);       // interleaved channel c'
    int src = (n & 3) * 64 + (n >> 2);        // original col: gate*64 + feature
    int kl  = (lane >> 4) * 8;
    constexpr int KX = KHW * CX;
    s16x8 vh, vl;
#pragma unroll
    for (int j = 0; j < 8; ++j) {
        int kg = ks * 32 + kl + j;
        float w = (kg < KX) ? Kw[(long)kg * 256 + src]
                            : Rw[(long)(kg - KX) * 256 + src];
        unsigned short h, l;
        split2(w, h, l);
        vh[j] = (short)h;
        vl[j] = (short)l;
    }
    unsigned short* o = Bw + (long)ks * 16384 + nfrag * 512 + lane * 8;
    *(s16x8*)o = vh;
    *(s16x8*)(o + 8192) = vl;
}

// ---- stage zero-padded tile as bf16 hi/lo planes, chunk-major [c/8][pixel][8] ----
template<int C, int TS, int PAD, int CST>
__device__ __forceinline__ void stage_split(const float* __restrict__ gp,
                                            unsigned short* __restrict__ hi_,
                                            unsigned short* __restrict__ lo_,
                                            int ty0, int tx0, int tid)
{
    constexpr int CH = C / 8;
    constexpr int NP = TS * TS;
    for (int i = tid; i < NP * CH; i += 512) {
        int ch = i % CH;
        int p  = i / CH;
        int py = p / TS, px = p % TS;
        int iy = ty0 + py - PAD, ix = tx0 + px - PAD;
        float v[8];
        if (iy >= 0 && iy < 64 && ix >= 0 && ix < 64) {
            const float* s = gp + ((long)(iy * 64 + ix)) * C + ch * 8;
            f32x4 a = *(const f32x4*)s;
            f32x4 b = *(const f32x4*)(s + 4);
#pragma unroll
            for (int j = 0; j < 4; ++j) { v[j] = a[j]; v[4 + j] = b[j]; }
        } else {
#pragma unroll
            for (int j = 0; j < 8; ++j) v[j] = 0.0f;
        }
        s16x8 vh, vl;
#pragma unroll
        for (int j = 0; j < 8; ++j) {
            unsigned short h, l;
            split2(v[j], h, l);
            vh[j] = (short)h;
            vl[j] = (short)l;
        }
        *(s16x8*)(hi_ + ch * CST + p * 8) = vh;
        *(s16x8*)(lo_ + ch * CST + p * 8) = vl;
    }
}

// ---- ConvLSTM step body: SWAPPED-OPERAND MFMA (z^T = W * X) ----
// 8 waves; wave w owns channels [32w, 32w+32) (2 A-frags) x ALL 64 pixels
// (4 B-frags), full K. Output D[row=channel][col=pixel]: pixel = lane&15,
// channel = (lane>>4)*4 + q. Gate-interleaved channels c' = 4f+g: each lane's
// q-regs = the 4 gates of one feature at one pixel -> gates/tanh/c-update all
// per-lane. Only hn is transposed (16.6 KB LDS plane, ONE barrier) so h/y
// stores stay fully coalesced (r14's scattered 4B stores cost +15 MB WRITE).
template<int KW, int CX, int TS, int NS, int XS>
__device__ __forceinline__ void lstm_body(
    unsigned short* __restrict__ smem,
    float* __restrict__ hplane,       // dedicated [64][65] f32 (no aliasing)
    const float* __restrict__ xin, long xbstride,
    const float* __restrict__ hin,
    const unsigned short* __restrict__ Bg,
    const float* __restrict__ bias,
    float* __restrict__ c_buf,        // feature-major: [b][f][4096]
    float* __restrict__ h_out,
    float* __restrict__ y_out, long ybstride,
    int b)
{
    constexpr int PAD = KW / 2;
    constexpr int NP  = TS * TS;
    constexpr int CHX = CX / 8;
    constexpr int CST = NP * 8;              // chunk stride (ushorts)
    constexpr int XPLANE = CHX * CST;
    constexpr int HPLANE = 8 * CST;

    unsigned short* sxh = smem;
    unsigned short* sxl = sxh + XPLANE;
    unsigned short* shh = sxl + XPLANE;
    unsigned short* shl = shh + HPLANE;

    const int tid  = threadIdx.x;
    const int lane = tid & 63, wid = tid >> 6;
    const int ty0 = blockIdx.y * 8, tx0 = blockIdx.x * 8;

    // W fragment stream: wave w owns nfrags {2w, 2w+1} = channels [32w, 32w+32)
    const unsigned short* bq = Bg + (2 * wid) * 512 + lane * 8;

    stage_split<CX, TS, PAD, CST>(xin + (long)b * xbstride, sxh, sxl, ty0, tx0, tid);
    stage_split<64, TS, PAD, CST>(hin + (long)b * 4096 * 64, shh, shl, ty0, tx0, tid);
    __syncthreads();

    f32x4 acc[2][4];   // [cf][pf]
#pragma unroll
    for (int cf = 0; cf < 2; ++cf)
#pragma unroll
        for (int pf = 0; pf < 4; ++pf)
#pragma unroll
            for (int q = 0; q < 4; ++q) acc[cf][pf][q] = 0.0f;

    // thread-const X offsets (ushort units). pixel p = pf*16 + (lane&15)
    const int pb  = lane & 15;
    const int kq  = (lane >> 4) * CST;
    const int av0 = (((pb      >> 3) * TS) + (pb      & 7)) * 8 + kq;
    const int av1 = ((((pb+16) >> 3) * TS) + ((pb+16) & 7)) * 8 + kq;
    const int av2 = ((((pb+32) >> 3) * TS) + ((pb+32) & 7)) * 8 + kq;
    const int av3 = ((((pb+48) >> 3) * TS) + ((pb+48) & 7)) * 8 + kq;

    // one k-step: W from L2 (4x16B), X from LDS (8x16B, immediate offsets),
    // 24 MFMA in 3 passes (WhXh, WhXl, WlXh), 8 independent acc chains.
#define KSTEP(PH, PL, SO)                                                 \
    {                                                                     \
        s16x8 Wh0 = *(const s16x8*)(bq);                                  \
        s16x8 Wh1 = *(const s16x8*)(bq + 512);                            \
        s16x8 Wl0 = *(const s16x8*)(bq + 8192);                           \
        s16x8 Wl1 = *(const s16x8*)(bq + 8192 + 512);                     \
        s16x8 X0h = *(const s16x8*)((PH) + (SO) + av0);                   \
        s16x8 X1h = *(const s16x8*)((PH) + (SO) + av1);                   \
        s16x8 X2h = *(const s16x8*)((PH) + (SO) + av2);                   \
        s16x8 X3h = *(const s16x8*)((PH) + (SO) + av3);                   \
        s16x8 X0l = *(const s16x8*)((PL) + (SO) + av0);                   \
        s16x8 X1l = *(const s16x8*)((PL) + (SO) + av1);                   \
        s16x8 X2l = *(const s16x8*)((PL) + (SO) + av2);                   \
        s16x8 X3l = *(const s16x8*)((PL) + (SO) + av3);                   \
        __builtin_amdgcn_s_setprio(1);                                    \
        acc[0][0] = MFMA16(Wh0, X0h, acc[0][0]);                          \
        acc[1][0] = MFMA16(Wh1, X0h, acc[1][0]);                          \
        acc[0][1] = MFMA16(Wh0, X1h, acc[0][1]);                          \
        acc[1][1] = MFMA16(Wh1, X1h, acc[1][1]);                          \
        acc[0][2] = MFMA16(Wh0, X2h, acc[0][2]);                          \
        acc[1][2] = MFMA16(Wh1, X2h, acc[1][2]);                          \
        acc[0][3] = MFMA16(Wh0, X3h, acc[0][3]);                          \
        acc[1][3] = MFMA16(Wh1, X3h, acc[1][3]);                          \
        acc[0][0] = MFMA16(Wh0, X0l, acc[0][0]);                          \
        acc[1][0] = MFMA16(Wh1, X0l, acc[1][0]);                          \
        acc[0][1] = MFMA16(Wh0, X1l, acc[0][1]);                          \
        acc[1][1] = MFMA16(Wh1, X1l, acc[1][1]);                          \
        acc[0][2] = MFMA16(Wh0, X2l, acc[0][2]);                          \
        acc[1][2] = MFMA16(Wh1, X2l, acc[1][2]);                          \
        acc[0][3] = MFMA16(Wh0, X3l, acc[0][3]);                          \
        acc[1][3] = MFMA16(Wh1, X3l, acc[1][3]);                          \
        acc[0][0] = MFMA16(Wl0, X0h, acc[0][0]);                          \
        acc[1][0] = MFMA16(Wl1, X0h, acc[1][0]);                          \
        acc[0][1] = MFMA16(Wl0, X1h, acc[0][1]);                          \
        acc[1][1] = MFMA16(Wl1, X1h, acc[1][1]);                          \
        acc[0][2] = MFMA16(Wl0, X2h, acc[0][2]);                          \
        acc[1][2] = MFMA16(Wl1, X2h, acc[1][2]);                          \
        acc[0][3] = MFMA16(Wl0, X3h, acc[0][3]);                          \
        acc[1][3] = MFMA16(Wl1, X3h, acc[1][3]);                          \
        __builtin_amdgcn_s_setprio(0);                                    \
        bq += 16384;                                                      \
    }

    // ---- x-phase ----
    if (CX == 32) {
#pragma unroll 1
        for (int kh = 0; kh < KW; ++kh) {
#pragma unroll
            for (int kw = 0; kw < KW; ++kw) {
                KSTEP(sxh, sxl, (kh * TS + kw) * 8);
            }
        }
    } else {
#pragma unroll 1
        for (int kh = 0; kh < KW; ++kh) {
#pragma unroll
            for (int kw = 0; kw < KW; ++kw) {
#pragma unroll
                for (int c2 = 0; c2 < 2; ++c2) {
                    KSTEP(sxh, sxl, c2 * 4 * CST + (kh * TS + kw) * 8);
                }
            }
        }
    }
    // ---- h-phase ----
#pragma unroll 1
    for (int kh = 0; kh < KW; ++kh) {
#pragma unroll
        for (int kw = 0; kw < KW; ++kw) {
#pragma unroll
            for (int c2 = 0; c2 < 2; ++c2) {
                KSTEP(shh, shl, c2 * 4 * CST + (kh * TS + kw) * 8);
            }
        }
    }
#undef KSTEP

    // ---- per-lane gates -> c update (feature-major, direct) + hn to LDS ----
    // Lane holds, per (cf,pf): gates q={i,f,g,o} of feature
    // f = wid*8 + cf*4 + (lane>>4) at pixel p = pf*16 + (lane&15).
    const int pxb = lane & 15;
    const int fq  = lane >> 4;
#pragma unroll
    for (int cf = 0; cf < 2; ++cf) {
        const int f = wid * 8 + cf * 4 + fq;
        const float bi  = bias[f];
        const float bfr = bias[64 + f];
        const float bg  = bias[128 + f];
        const float bo  = bias[192 + f];
#pragma unroll
        for (int pf = 0; pf < 4; ++pf) {
            int p  = pf * 16 + pxb;
            int gp = (ty0 + (p >> 3)) * 64 + (tx0 + (p & 7));
            long oc = ((long)(b * 64 + f)) * 4096 + gp;  // c: feature-major
            float zi = acc[cf][pf][0] + bi;
            float zf = acc[cf][pf][1] + bfr;
            float zg = acc[cf][pf][2] + bg;
            float zo = acc[cf][pf][3] + bo;
            float cv = c_buf[oc];
            float cn = hsig(zf) * cv + hsig(zi) * tanhf(zg);
            c_buf[oc] = cn;
            hplane[p * 65 + f] = hsig(zo) * tanhf(cn);
        }
    }
    __syncthreads();

    // ---- coalesced h/y write: lane = feature, 256B-contiguous stores ----
    const int f = tid & 63;
#pragma unroll
    for (int j = 0; j < 8; ++j) {
        int p  = (tid >> 6) + j * 8;             // 0..63
        int yy = ty0 + (p >> 3), xx = tx0 + (p & 7);
        int gp = yy * 64 + xx;
        float hn = hplane[p * 65 + f];
        long o = ((long)(b * 64 + yy) * 64 + xx) * 64 + f;
        h_out[o] = hn;
        y_out[(long)b * ybstride + (long)gp * 64 + f] = fmaxf(hn, 0.0f);
    }
}

// ---- fused dual-layer launch: z<4 -> layer1 step t, z>=4 -> layer2 step t-1 ----
// LDS: stage 55296 B (L1) + hn plane 16640 B = 71936 B; 2 blocks = 143.9 KB
// <= 160 KB -> co-residency preserved (r7 proved >=133 KB co-resides).
__global__ __launch_bounds__(512, 2)
void lstm_fused(
    const float* __restrict__ x1, const float* __restrict__ h1in,
    const unsigned short* __restrict__ B1g, const float* __restrict__ bias1,
    float* __restrict__ c1, float* __restrict__ h1out, float* __restrict__ y1out,
    const float* __restrict__ x2, const float* __restrict__ h2in,
    const unsigned short* __restrict__ B2g, const float* __restrict__ bias2,
    float* __restrict__ c2, float* __restrict__ h2out, float* __restrict__ y2out,
    int mode)
{
    __shared__ __align__(16) unsigned short smem[27648];  // stage (55296 B)
    __shared__ __align__(16) float hplane[64 * 65];       // hn plane (16640 B)
    const int z = blockIdx.z;
    const int b = z & 3;
    const bool doL2 = (mode == 1) || (z >= 4);
    if (!doL2) {
        lstm_body<5, 32, 12, 75, 25>(smem, hplane, x1, (long)8 * 4096 * 32, h1in,
                                     B1g, bias1, c1, h1out,
                                     y1out, (long)8 * 4096 * 64, b);
    } else {
        lstm_body<3, 64, 10, 36, 18>(smem, hplane, x2, (long)8 * 4096 * 64, h2in,
                                     B2g, bias2, c2, h2out,
                                     y2out, (long)8 * 4096 * 64, b);
    }
}

extern "C" void kernel_launch(void* const* d_in, const int* in_sizes, int n_in,
                              void* d_out, int out_size, void* d_ws, size_t ws_size,
                              hipStream_t stream)
{
    const float* x  = (const float*)d_in[0];
    const float* K1 = (const float*)d_in[1];
    const float* R1 = (const float*)d_in[2];
    const float* b1 = (const float*)d_in[3];
    const float* K2 = (const float*)d_in[4];
    const float* R2 = (const float*)d_in[5];
    const float* b2 = (const float*)d_in[6];
    float* out = (float*)d_out;

    const long HW   = 4096;
    const long SZ_S = HW * 64 * 4;      // 1,048,576 floats per [B,H,W,64]
    const long SZ_Y = SZ_S * 8;

    float* ws  = (float*)d_ws;
    float* y1  = ws;                    // 8,388,608 f32 ([B][T][HW][64])
    float* h1a = y1 + SZ_Y;
    float* h1b = h1a + SZ_S;
    float* h2a = h1b + SZ_S;
    float* h2b = h2a + SZ_S;
    float* c1  = h2b + SZ_S;
    float* c2  = c1 + SZ_S;
    unsigned short* B1 = (unsigned short*)(c2 + SZ_S);   // 75*16384 ushorts
    unsigned short* B2 = B1 + (long)75 * 16384;          // 36*16384 ushorts

    // weight prep
    prep_w<25, 32, 75><<<300, 256, 0, stream>>>(K1, R1, B1);
    prep_w<9,  64, 36><<<144, 256, 0, stream>>>(K2, R2, B2);

    hipMemsetAsync(h1a, 0, (size_t)SZ_S * sizeof(float), stream);
    hipMemsetAsync(c1,  0, (size_t)SZ_S * sizeof(float), stream);
    hipMemsetAsync(h2a, 0, (size_t)SZ_S * sizeof(float), stream);
    hipMemsetAsync(c2,  0, (size_t)SZ_S * sizeof(float), stream);

    float* hp1 = h1a; float* hn1 = h1b;
    float* hp2 = h2a; float* hn2 = h2b;

    for (int t = 0; t <= 8; ++t) {
        const int mode = (t == 0) ? 0 : (t == 8) ? 1 : 2;
        const int t1  = (t <= 7) ? t : 7;       // L1 timestep (unused at t=8)
        const int tm1 = (t >= 1) ? t - 1 : 0;   // L2 timestep (unused at t=0)
        dim3 grid(8, 8, mode == 2 ? 8 : 4);
        lstm_fused<<<grid, 512, 0, stream>>>(
            x  + (long)t1 * HW * 32,  hp1, B1, b1, c1, hn1,
            y1 + (long)t1 * HW * 64,
            y1 + (long)tm1 * HW * 64, hp2, B2, b2, c2, hn2,
            out + (long)tm1 * HW * 64,
            mode);
        if (mode != 1) { float* tmp = hp1; hp1 = hn1; hn1 = tmp; }
        if (mode != 0) { float* tmp = hp2; hp2 = hn2; hn2 = tmp; }
    }
}

// Round 16
// 469.180 us; speedup vs baseline: 1.3388x; 1.3160x over previous
//
#include <hip/hip_runtime.h>

typedef __attribute__((ext_vector_type(4))) float f32x4;
typedef __attribute__((ext_vector_type(8))) short s16x8;

#define MFMA16(a, b, c) __builtin_amdgcn_mfma_f32_16x16x32_bf16((a), (b), (c), 0, 0, 0)

__device__ __forceinline__ float hsig(float x) {
    return fminf(fmaxf(0.2f * x + 0.5f, 0.0f), 1.0f);
}

__device__ __forceinline__ unsigned short bf16rne(float v) {
    unsigned u = __float_as_uint(v);
    u += 0x7FFFu + ((u >> 16) & 1u);
    return (unsigned short)(u >> 16);
}
__device__ __forceinline__ void split2(float v, unsigned short& h, unsigned short& l) {
    h = bf16rne(v);
    float hv = __uint_as_float((unsigned)h << 16);
    l = bf16rne(v - hv);
}

// ---- weight prep: MFMA A-fragment order, GATE-INTERLEAVED rows, hi/lo split ----
// Bw layout: [ks][ hi: nfrag(16) x lane(64) x 8 | lo: same ]  (16384 ushorts per ks)
// Row n = output channel in interleaved order c' = 4*feature + gate.
template<int KHW, int CX, int NS>
__global__ __launch_bounds__(256)
void prep_w(const float* __restrict__ Kw, const float* __restrict__ Rw,
            unsigned short* __restrict__ Bw)
{
    int gid = blockIdx.x * 256 + threadIdx.x;
    if (gid >= NS * 1024) return;
    int lane  = gid & 63;
    int nfrag = (gid >> 6) & 15;
    int ks    = gid >> 10;
    int n   = nfrag * 16 + (lane & 15);       // interleaved channel c'
    int src = (n & 3) * 64 + (n >> 2);        // original col: gate*64 + feature
    int kl  = (lane >> 4) * 8;
    constexpr int KX = KHW * CX;
    s16x8 vh, vl;
#pragma unroll
    for (int j = 0; j < 8; ++j) {
        int kg = ks * 32 + kl + j;
        float w = (kg < KX) ? Kw[(long)kg * 256 + src]
                            : Rw[(long)(kg - KX) * 256 + src];
        unsigned short h, l;
        split2(w, h, l);
        vh[j] = (short)h;
        vl[j] = (short)l;
    }
    unsigned short* o = Bw + (long)ks * 16384 + nfrag * 512 + lane * 8;
    *(s16x8*)o = vh;
    *(s16x8*)(o + 8192) = vl;
}

// ---- stage zero-padded tile as SINGLE bf16 plane (RNE), chunk-major ----
// X is rounded once to bf16; W stays hi/lo-exact. 2-pass scheme:
// z = Wh*X + Wl*X. Halves LDS traffic and staging VALU vs the 3-pass.
template<int C, int TS, int PAD, int CST>
__device__ __forceinline__ void stage_bf16(const float* __restrict__ gp,
                                           unsigned short* __restrict__ dst,
                                           int ty0, int tx0, int tid)
{
    constexpr int CH = C / 8;
    constexpr int NP = TS * TS;
    for (int i = tid; i < NP * CH; i += 512) {
        int ch = i % CH;
        int p  = i / CH;
        int py = p / TS, px = p % TS;
        int iy = ty0 + py - PAD, ix = tx0 + px - PAD;
        s16x8 vb;
        if (iy >= 0 && iy < 64 && ix >= 0 && ix < 64) {
            const float* s = gp + ((long)(iy * 64 + ix)) * C + ch * 8;
            f32x4 a = *(const f32x4*)s;
            f32x4 b = *(const f32x4*)(s + 4);
#pragma unroll
            for (int j = 0; j < 4; ++j) {
                vb[j]     = (short)bf16rne(a[j]);
                vb[4 + j] = (short)bf16rne(b[j]);
            }
        } else {
#pragma unroll
            for (int j = 0; j < 8; ++j) vb[j] = 0;
        }
        *(s16x8*)(dst + ch * CST + p * 8) = vb;
    }
}

// ---- ConvLSTM step body: swapped-operand MFMA (z^T = W * X), 2-pass ----
// 8 waves; wave w owns channels [32w,32w+32) x ALL 64 pixels, full K.
// 16 MFMA/k-step (was 24): floor 103K -> 69K cyc/CU. A-LDS reads halve.
// Gate-interleaved channels: lane's 4 q-regs = the 4 gates of one feature;
// gates/tanh/c-update per-lane; hn transposed via one LDS plane + 1 barrier.
template<int KW, int CX, int TS, int NS, int XS>
__device__ __forceinline__ void lstm_body(
    unsigned short* __restrict__ smem,
    float* __restrict__ hplane,       // [64][65] f32, dedicated
    const float* __restrict__ xin, long xbstride,
    const float* __restrict__ hin,
    const unsigned short* __restrict__ Bg,
    const float* __restrict__ bias,
    float* __restrict__ c_buf,        // thread-keyed coalesced (internal)
    float* __restrict__ h_out,
    float* __restrict__ y_out, long ybstride,
    int b)
{
    constexpr int PAD = KW / 2;
    constexpr int NP  = TS * TS;
    constexpr int CHX = CX / 8;
    constexpr int CST = NP * 8;              // chunk stride (ushorts)
    constexpr int XPLANE = CHX * CST;

    unsigned short* sx = smem;               // x plane (CHX chunks)
    unsigned short* sh = sx + XPLANE;        // h plane (8 chunks)

    const int tid  = threadIdx.x;
    const int lane = tid & 63, wid = tid >> 6;
    const int ty0 = blockIdx.y * 8, tx0 = blockIdx.x * 8;

    // W fragment stream: wave w owns nfrags {2w, 2w+1} = channels [32w, 32w+32)
    const unsigned short* bq = Bg + (2 * wid) * 512 + lane * 8;

    stage_bf16<CX, TS, PAD, CST>(xin + (long)b * xbstride, sx, ty0, tx0, tid);
    stage_bf16<64, TS, PAD, CST>(hin + (long)b * 4096 * 64, sh, ty0, tx0, tid);
    __syncthreads();

    f32x4 acc[2][4];   // [cf][pf]
#pragma unroll
    for (int cf = 0; cf < 2; ++cf)
#pragma unroll
        for (int pf = 0; pf < 4; ++pf)
#pragma unroll
            for (int q = 0; q < 4; ++q) acc[cf][pf][q] = 0.0f;

    // thread-const X offsets (ushort units). pixel p = pf*16 + (lane&15)
    const int pb  = lane & 15;
    const int kq  = (lane >> 4) * CST;
    const int av0 = (((pb      >> 3) * TS) + (pb      & 7)) * 8 + kq;
    const int av1 = ((((pb+16) >> 3) * TS) + ((pb+16) & 7)) * 8 + kq;
    const int av2 = ((((pb+32) >> 3) * TS) + ((pb+32) & 7)) * 8 + kq;
    const int av3 = ((((pb+48) >> 3) * TS) + ((pb+48) & 7)) * 8 + kq;

    // one k-step: W hi/lo from L2 (4x16B), X from LDS (4x16B), 16 MFMA.
#define KSTEP(PX, SO)                                                     \
    {                                                                     \
        s16x8 Wh0 = *(const s16x8*)(bq);                                  \
        s16x8 Wh1 = *(const s16x8*)(bq + 512);                            \
        s16x8 Wl0 = *(const s16x8*)(bq + 8192);                           \
        s16x8 Wl1 = *(const s16x8*)(bq + 8192 + 512);                     \
        s16x8 X0 = *(const s16x8*)((PX) + (SO) + av0);                    \
        s16x8 X1 = *(const s16x8*)((PX) + (SO) + av1);                    \
        s16x8 X2 = *(const s16x8*)((PX) + (SO) + av2);                    \
        s16x8 X3 = *(const s16x8*)((PX) + (SO) + av3);                    \
        __builtin_amdgcn_s_setprio(1);                                    \
        acc[0][0] = MFMA16(Wh0, X0, acc[0][0]);                           \
        acc[1][0] = MFMA16(Wh1, X0, acc[1][0]);                           \
        acc[0][1] = MFMA16(Wh0, X1, acc[0][1]);                           \
        acc[1][1] = MFMA16(Wh1, X1, acc[1][1]);                           \
        acc[0][2] = MFMA16(Wh0, X2, acc[0][2]);                           \
        acc[1][2] = MFMA16(Wh1, X2, acc[1][2]);                           \
        acc[0][3] = MFMA16(Wh0, X3, acc[0][3]);                           \
        acc[1][3] = MFMA16(Wh1, X3, acc[1][3]);                           \
        acc[0][0] = MFMA16(Wl0, X0, acc[0][0]);                           \
        acc[1][0] = MFMA16(Wl1, X0, acc[1][0]);                           \
        acc[0][1] = MFMA16(Wl0, X1, acc[0][1]);                           \
        acc[1][1] = MFMA16(Wl1, X1, acc[1][1]);                           \
        acc[0][2] = MFMA16(Wl0, X2, acc[0][2]);                           \
        acc[1][2] = MFMA16(Wl1, X2, acc[1][2]);                           \
        acc[0][3] = MFMA16(Wl0, X3, acc[0][3]);                           \
        acc[1][3] = MFMA16(Wl1, X3, acc[1][3]);                           \
        __builtin_amdgcn_s_setprio(0);                                    \
        bq += 16384;                                                      \
    }

    // ---- x-phase (k-step order matches prep_w) ----
    if (CX == 32) {
#pragma unroll 1
        for (int kh = 0; kh < KW; ++kh) {
#pragma unroll
            for (int kw = 0; kw < KW; ++kw) {
                KSTEP(sx, (kh * TS + kw) * 8);
            }
        }
    } else {
#pragma unroll 1
        for (int kh = 0; kh < KW; ++kh) {
#pragma unroll
            for (int kw = 0; kw < KW; ++kw) {
#pragma unroll
                for (int c2 = 0; c2 < 2; ++c2) {
                    KSTEP(sx, c2 * 4 * CST + (kh * TS + kw) * 8);
                }
            }
        }
    }
    // ---- h-phase (C=64) ----
#pragma unroll 1
    for (int kh = 0; kh < KW; ++kh) {
#pragma unroll
        for (int kw = 0; kw < KW; ++kw) {
#pragma unroll
            for (int c2 = 0; c2 < 2; ++c2) {
                KSTEP(sh, c2 * 4 * CST + (kh * TS + kw) * 8);
            }
        }
    }
#undef KSTEP

    // ---- per-lane gates -> c update (thread-keyed coalesced) + hn to LDS ----
    // Lane holds gates q={i,f,g,o} of feature f = wid*8 + cf*4 + (lane>>4)
    // at pixel p = pf*16 + (lane&15).
    const int pxb  = lane & 15;
    const int fq   = lane >> 4;
    const int tile = blockIdx.y * 8 + blockIdx.x;
    const long cb0 = (((long)b * 64 + tile) * 8) * 512 + tid;
#pragma unroll
    for (int cf = 0; cf < 2; ++cf) {
        const int f = wid * 8 + cf * 4 + fq;
        const float bi  = bias[f];
        const float bfr = bias[64 + f];
        const float bg  = bias[128 + f];
        const float bo  = bias[192 + f];
#pragma unroll
        for (int pf = 0; pf < 4; ++pf) {
            int p   = pf * 16 + pxb;
            long oc = cb0 + (long)(cf * 4 + pf) * 512;   // 512 threads x 4B
            float zi = acc[cf][pf][0] + bi;
            float zf = acc[cf][pf][1] + bfr;
            float zg = acc[cf][pf][2] + bg;
            float zo = acc[cf][pf][3] + bo;
            float cv = c_buf[oc];
            float cn = hsig(zf) * cv + hsig(zi) * tanhf(zg);
            c_buf[oc] = cn;
            hplane[p * 65 + f] = hsig(zo) * tanhf(cn);
        }
    }
    __syncthreads();

    // ---- coalesced h/y write: lane = feature, 256B-contiguous stores ----
    const int f = tid & 63;
#pragma unroll
    for (int j = 0; j < 8; ++j) {
        int p  = (tid >> 6) + j * 8;             // 0..63
        int yy = ty0 + (p >> 3), xx = tx0 + (p & 7);
        int gp = yy * 64 + xx;
        float hn = hplane[p * 65 + f];
        long o = ((long)(b * 64 + yy) * 64 + xx) * 64 + f;
        h_out[o] = hn;
        y_out[(long)b * ybstride + (long)gp * 64 + f] = fmaxf(hn, 0.0f);
    }
}

// ---- fused dual-layer launch: z<4 -> layer1 step t, z>=4 -> layer2 step t-1 ----
// LDS: stage max(12,16 chunks) 27.6 KB + hn plane 16.6 KB = 44.3 KB/block;
// 2 blocks = 88.6 KB, well under 160 KB. Regs ~45 arch + 32 acc -> co-resident.
__global__ __launch_bounds__(512, 2)
void lstm_fused(
    const float* __restrict__ x1, const float* __restrict__ h1in,
    const unsigned short* __restrict__ B1g, const float* __restrict__ bias1,
    float* __restrict__ c1, float* __restrict__ h1out, float* __restrict__ y1out,
    const float* __restrict__ x2, const float* __restrict__ h2in,
    const unsigned short* __restrict__ B2g, const float* __restrict__ bias2,
    float* __restrict__ c2, float* __restrict__ h2out, float* __restrict__ y2out,
    int mode)
{
    // L1: (4+8)*1152 = 13824 u16; L2: (8+8)*800 = 12800 u16 -> max 13824
    __shared__ __align__(16) unsigned short smem[13824];
    __shared__ __align__(16) float hplane[64 * 65];
    const int z = blockIdx.z;
    const int b = z & 3;
    const bool doL2 = (mode == 1) || (z >= 4);
    if (!doL2) {
        lstm_body<5, 32, 12, 75, 25>(smem, hplane, x1, (long)8 * 4096 * 32, h1in,
                                     B1g, bias1, c1, h1out,
                                     y1out, (long)8 * 4096 * 64, b);
    } else {
        lstm_body<3, 64, 10, 36, 18>(smem, hplane, x2, (long)8 * 4096 * 64, h2in,
                                     B2g, bias2, c2, h2out,
                                     y2out, (long)8 * 4096 * 64, b);
    }
}

extern "C" void kernel_launch(void* const* d_in, const int* in_sizes, int n_in,
                              void* d_out, int out_size, void* d_ws, size_t ws_size,
                              hipStream_t stream)
{
    const float* x  = (const float*)d_in[0];
    const float* K1 = (const float*)d_in[1];
    const float* R1 = (const float*)d_in[2];
    const float* b1 = (const float*)d_in[3];
    const float* K2 = (const float*)d_in[4];
    const float* R2 = (const float*)d_in[5];
    const float* b2 = (const float*)d_in[6];
    float* out = (float*)d_out;

    const long HW   = 4096;
    const long SZ_S = HW * 64 * 4;      // 1,048,576 floats per [B,H,W,64]
    const long SZ_Y = SZ_S * 8;

    float* ws  = (float*)d_ws;
    float* y1  = ws;                    // 8,388,608 f32 ([B][T][HW][64])
    float* h1a = y1 + SZ_Y;
    float* h1b = h1a + SZ_S;
    float* h2a = h1b + SZ_S;
    float* h2b = h2a + SZ_S;
    float* c1  = h2b + SZ_S;
    float* c2  = c1 + SZ_S;
    unsigned short* B1 = (unsigned short*)(c2 + SZ_S);   // 75*16384 ushorts
    unsigned short* B2 = B1 + (long)75 * 16384;          // 36*16384 ushorts

    // weight prep
    prep_w<25, 32, 75><<<300, 256, 0, stream>>>(K1, R1, B1);
    prep_w<9,  64, 36><<<144, 256, 0, stream>>>(K2, R2, B2);

    hipMemsetAsync(h1a, 0, (size_t)SZ_S * sizeof(float), stream);
    hipMemsetAsync(c1,  0, (size_t)SZ_S * sizeof(float), stream);
    hipMemsetAsync(h2a, 0, (size_t)SZ_S * sizeof(float), stream);
    hipMemsetAsync(c2,  0, (size_t)SZ_S * sizeof(float), stream);

    float* hp1 = h1a; float* hn1 = h1b;
    float* hp2 = h2a; float* hn2 = h2b;

    for (int t = 0; t <= 8; ++t) {
        const int mode = (t == 0) ? 0 : (t == 8) ? 1 : 2;
        const int t1  = (t <= 7) ? t : 7;       // L1 timestep (unused at t=8)
        const int tm1 = (t >= 1) ? t - 1 : 0;   // L2 timestep (unused at t=0)
        dim3 grid(8, 8, mode == 2 ? 8 : 4);
        lstm_fused<<<grid, 512, 0, stream>>>(
            x  + (long)t1 * HW * 32,  hp1, B1, b1, c1, hn1,
            y1 + (long)t1 * HW * 64,
            y1 + (long)tm1 * HW * 64, hp2, B2, b2, c2, hn2,
            out + (long)tm1 * HW * 64,
            mode);
        if (mode != 1) { float* tmp = hp1; hp1 = hn1; hn1 = tmp; }
        if (mode != 0) { float* tmp = hp2; hp2 = hn2; hn2 = tmp; }
    }
}